// Round 1
// baseline (319.890 us; speedup 1.0000x reference)
//
#include <hip/hip_runtime.h>

constexpr int Bn = 2;
constexpr int Nn = 16384;
constexpr int Cc = 128;
constexpr int VFh = 3;
constexpr int Vv = Nn * VFh;        // 49152
constexpr int Pp = 4;
constexpr int M3 = (3 + Cc) * VFh;  // 393
constexpr int NB = 192;             // radix blocks per sample, 256 elems each
constexpr int HB = 96;              // head blocks per sample, 512 elems each

// out layout (flat float32, reference return order)
constexpr size_t IND0  = 0;
constexpr size_t COOR0 = (size_t)Bn * Vv * 3;                  // 294912
constexpr size_t FEAT0 = COOR0 + (size_t)Bn * Vv * Pp * 3;     // 1474560
constexpr size_t MASK0 = FEAT0 + (size_t)Bn * Vv * Pp * Cc;    // 51806208

// ---------------- GEMM: out[n][m] = sum_k A[n][k]*W[m][k] + bias[m] ----------------
// A: [B][N][128] rows; W: [M][128]; out: [B][N][ldo]
__global__ __launch_bounds__(256) void gemm_k128(
    const float* __restrict__ A, const float* __restrict__ W,
    const float* __restrict__ bias, float* __restrict__ out,
    int M, int ldo, int nRB, int nCB)
{
    __shared__ float As[64 * 72];  // stride 72: conflict-free for row=i*16+ty reads
    __shared__ float Ws[64 * 68];  // stride 68: 2-way (free) for row=j*16+tx reads

    int bid = blockIdx.x;
    int s  = bid / (nRB * nCB);
    int r  = bid % (nRB * nCB);
    int rb = r / nCB, cb = r % nCB;
    int m0 = cb * 64;

    const float* Ag = A + (size_t)s * Nn * Cc + (size_t)rb * 64 * Cc;
    const float* Wg = W + (size_t)m0 * Cc;
    float* outg = out + (size_t)s * Nn * ldo + (size_t)rb * 64 * ldo;

    int t  = threadIdx.x;
    int tx = t & 15, ty = t >> 4;

    float acc[4][4] = {};

    for (int half = 0; half < 2; ++half) {
        int k0 = half * 64;
        if (half) __syncthreads();  // protect LDS reuse
        // stage 64x64 of A and W
        #pragma unroll
        for (int rep = 0; rep < 4; ++rep) {
            int idx = rep * 256 + t;
            int row = idx >> 4;
            int c4  = (idx & 15) * 4;
            *(float4*)&As[row * 72 + c4] = *(const float4*)(Ag + (size_t)row * Cc + k0 + c4);
            float4 wv = make_float4(0.f, 0.f, 0.f, 0.f);
            if (m0 + row < M) wv = *(const float4*)(Wg + (size_t)row * Cc + k0 + c4);
            *(float4*)&Ws[row * 68 + c4] = wv;
        }
        __syncthreads();
        #pragma unroll
        for (int k4 = 0; k4 < 16; ++k4) {
            int k = k4 * 4;
            float4 av[4], wv[4];
            #pragma unroll
            for (int i = 0; i < 4; ++i) av[i] = *(const float4*)&As[(i * 16 + ty) * 72 + k];
            #pragma unroll
            for (int j = 0; j < 4; ++j) wv[j] = *(const float4*)&Ws[(j * 16 + tx) * 68 + k];
            #pragma unroll
            for (int i = 0; i < 4; ++i)
                #pragma unroll
                for (int j = 0; j < 4; ++j) {
                    float sacc = acc[i][j];
                    sacc += av[i].x * wv[j].x;
                    sacc += av[i].y * wv[j].y;
                    sacc += av[i].z * wv[j].z;
                    sacc += av[i].w * wv[j].w;
                    acc[i][j] = sacc;
                }
        }
    }
    #pragma unroll
    for (int j = 0; j < 4; ++j) {
        int m = m0 + j * 16 + tx;
        if (m < M) {
            float bv = bias[m];
            #pragma unroll
            for (int i = 0; i < 4; ++i)
                outg[(size_t)(i * 16 + ty) * ldo + m] = acc[i][j] + bv;
        }
    }
}

// ---------------- deterministic column stats (sum, sumsq) ----------------
__global__ void colstats(const float* __restrict__ Y, float* __restrict__ part)
{   // grid: B*64 blocks, 128 threads; 256 rows per block
    int blk = blockIdx.x;
    int s = blk >> 6, b = blk & 63;
    const float* Yp = Y + (size_t)s * Nn * Cc + (size_t)b * 256 * Cc;
    int c = threadIdx.x;
    float sm = 0.f, sq = 0.f;
    for (int r = 0; r < 256; ++r) {
        float v = Yp[(size_t)r * Cc + c];
        sm += v; sq += v * v;
    }
    float* pp = part + ((size_t)s * 64 + b) * 2 * Cc;
    pp[c] = sm;
    pp[Cc + c] = sq;
}

__global__ void bnfinalize(const float* __restrict__ part, const float* __restrict__ g,
                           const float* __restrict__ be, float* __restrict__ ss)
{   // grid: B blocks, 128 threads; ss: [s][scale(128), shift(128)]
    int s = blockIdx.x, c = threadIdx.x;
    const float* pp = part + (size_t)s * 64 * 2 * Cc;
    float sm = 0.f, sq = 0.f;
    for (int b = 0; b < 64; ++b) {
        sm += pp[(size_t)b * 2 * Cc + c];
        sq += pp[(size_t)b * 2 * Cc + Cc + c];
    }
    float m   = sm / (float)Nn;
    float var = sq / (float)Nn - m * m;
    float inv = 1.0f / sqrtf(var + 1e-5f);
    float sc  = g[c] * inv;
    ss[(size_t)s * 2 * Cc + c]      = sc;
    ss[(size_t)s * 2 * Cc + Cc + c] = be[c] - m * sc;
}

__global__ void bnrelu(const float* __restrict__ Y, const float* __restrict__ ss,
                       float* __restrict__ H)
{   // elementwise float4 over B*N*C
    int i = blockIdx.x * blockDim.x + threadIdx.x;       // float4 index
    int s = i / (Nn * Cc / 4);
    float4 v = ((const float4*)Y)[i];
    int c = (i & 31) * 4;  // (i*4) % 128
    const float* sp = ss + (size_t)s * 2 * Cc;
    float4 o;
    o.x = fmaxf(0.f, v.x * sp[c + 0] + sp[Cc + c + 0]);
    o.y = fmaxf(0.f, v.y * sp[c + 1] + sp[Cc + c + 1]);
    o.z = fmaxf(0.f, v.z * sp[c + 2] + sp[Cc + c + 2]);
    o.w = fmaxf(0.f, v.w * sp[c + 3] + sp[Cc + c + 3]);
    ((float4*)H)[i] = o;
}

// ---------------- vote prep: coor / ind / keys / feat_base ----------------
__global__ void prep(const float* __restrict__ LOG, const float* __restrict__ FT,
                     const float* __restrict__ CO, const int* __restrict__ ID,
                     float* __restrict__ coor, int* __restrict__ indb,
                     float* __restrict__ featb, unsigned* __restrict__ keys,
                     unsigned* __restrict__ idx0)
{   // grid: B*N blocks, 128 threads
    int blk = blockIdx.x;
    int s = blk >> 14, n = blk & 16383;
    const float* Lr = LOG + ((size_t)s * Nn + n) * M3;
    int t = threadIdx.x;
    // feat_base[n] = ftv[n] + log[n, VF-1, 3:] * (3/VF == 1.0)
    featb[((size_t)s * Nn + n) * Cc + t] =
        FT[((size_t)s * Nn + n) * Cc + t] + Lr[2 * 131 + 3 + t];
    if (t < 3) {
        int j = t;
        float o0 = Lr[j * 131 + 0], o1 = Lr[j * 131 + 1], o2 = Lr[j * 131 + 2];
        int v = n * 3 + j;
        size_t vb = (size_t)s * Vv + v;
        const float* co = CO + ((size_t)s * Nn + n) * 3;
        coor[vb * 3 + 0] = co[0] + o0;
        coor[vb * 3 + 1] = co[1] + o1;
        coor[vb * 3 + 2] = co[2] + o2;
        const int* id = ID + ((size_t)s * Nn + n) * 3;
        int gi0 = (int)(o0 / 0.1f), gi1 = (int)(o1 / 0.1f), gi2 = (int)(o2 / 0.1f);
        int i0 = id[0] + gi0, i1 = id[1] + gi1, i2 = id[2] + gi2;
        indb[vb * 3 + 0] = i0; indb[vb * 3 + 1] = i1; indb[vb * 3 + 2] = i2;
        int h0 = min(max(i0, -512), 511) + 512;
        int h1 = min(max(i1, -512), 511) + 512;
        int h2 = min(max(i2, -512), 511) + 512;
        keys[vb] = ((unsigned)h0 * 1024u + (unsigned)h1) * 1024u + (unsigned)h2;
        idx0[vb] = (unsigned)v;
    }
}

// ---------------- LSD radix sort, 3 x 10-bit passes ----------------
__global__ void rhist(const unsigned* __restrict__ keys, unsigned* __restrict__ hist, int shift)
{   // grid: B*NB, 256 threads
    __shared__ unsigned h[1024];
    int t = threadIdx.x;
    for (int i = t; i < 1024; i += 256) h[i] = 0;
    __syncthreads();
    int blk = blockIdx.x;
    int s = blk / NB, b = blk % NB;
    unsigned key = keys[(size_t)s * Vv + b * 256 + t];
    unsigned d = (key >> shift) & 1023u;
    atomicAdd(&h[d], 1u);
    __syncthreads();
    unsigned* hg = hist + (size_t)s * 1024 * NB;
    for (int i = t; i < 1024; i += 256) hg[(size_t)i * NB + b] = h[i];
}

__global__ void rscan1(unsigned* __restrict__ hist, unsigned* __restrict__ binTotal)
{   // grid: B*4 blocks, 256 threads; one thread per bin: exclusive scan along blocks
    int gid = blockIdx.x * 256 + threadIdx.x;  // 0..2047
    int s = gid >> 10, d = gid & 1023;
    unsigned* hp = hist + (size_t)s * 1024 * NB + (size_t)d * NB;
    unsigned run = 0;
    for (int b = 0; b < NB; ++b) { unsigned v = hp[b]; hp[b] = run; run += v; }
    binTotal[gid] = run;
}

__global__ void rscan2(const unsigned* __restrict__ binTotal, unsigned* __restrict__ binBase)
{   // grid: B blocks, 1024 threads: exclusive scan over bins
    __shared__ unsigned sh[1024];
    int s = blockIdx.x, t = threadIdx.x;
    unsigned v = binTotal[s * 1024 + t];
    sh[t] = v;
    __syncthreads();
    for (int off = 1; off < 1024; off <<= 1) {
        unsigned add = (t >= off) ? sh[t - off] : 0u;
        __syncthreads();
        sh[t] += add;
        __syncthreads();
    }
    binBase[s * 1024 + t] = sh[t] - v;
}

__global__ void rscatter(const unsigned* __restrict__ keysIn, const unsigned* __restrict__ idxIn,
                         unsigned* __restrict__ keysOut, unsigned* __restrict__ idxOut,
                         const unsigned* __restrict__ hist, const unsigned* __restrict__ binBase,
                         int shift)
{   // grid: B*NB, 256 threads; stable scatter
    __shared__ unsigned h[1024];
    int t = threadIdx.x;
    for (int i = t; i < 1024; i += 256) h[i] = 0;
    __syncthreads();
    int blk = blockIdx.x;
    int s = blk / NB, b = blk % NB;
    size_t base = (size_t)s * Vv + b * 256 + t;
    unsigned key = keysIn[base], idx = idxIn[base];
    unsigned d = (key >> shift) & 1023u;
    // wave match-any over 10-bit digit
    unsigned long long m = ~0ull;
    #pragma unroll
    for (int bit = 0; bit < 10; ++bit) {
        bool bb = (d >> bit) & 1u;
        unsigned long long bal = __ballot(bb);
        m &= bb ? bal : ~bal;
    }
    int lane = t & 63, wid = t >> 6;
    int lanesBelow = __popcll(m & ((1ull << lane) - 1ull));
    int cnt = __popcll(m);
    int leader = __ffsll((unsigned long long)m) - 1;
    unsigned basecnt = 0;
    for (int w = 0; w < 4; ++w) {
        if (wid == w) {
            basecnt = h[d];                          // read (lockstep, before write)
            if (lane == leader) h[d] = basecnt + (unsigned)cnt;
        }
        __syncthreads();
    }
    unsigned localRank = basecnt + (unsigned)lanesBelow;
    const unsigned* hg = hist + (size_t)s * 1024 * NB;
    unsigned dest = binBase[s * 1024 + (int)d] + hg[(size_t)d * NB + b] + localRank;
    keysOut[(size_t)s * Vv + dest] = key;
    idxOut[(size_t)s * Vv + dest]  = idx;
}

// ---------------- group heads / ranks / starts ----------------
__global__ void heads(const unsigned* __restrict__ skeys, unsigned* __restrict__ hpart)
{   // grid: B*HB, 512 threads
    int blk = blockIdx.x;
    int s = blk / HB, b = blk % HB;
    int i = b * 512 + threadIdx.x;
    size_t base = (size_t)s * Vv;
    unsigned k = skeys[base + i];
    bool head = (i == 0) || (skeys[base + i - 1] != k);
    __shared__ unsigned wsum[8];
    unsigned long long bal = __ballot(head);
    int lane = threadIdx.x & 63, wid = threadIdx.x >> 6;
    if (lane == 0) wsum[wid] = (unsigned)__popcll(bal);
    __syncthreads();
    if (threadIdx.x == 0) {
        unsigned tot = 0;
        for (int w = 0; w < 8; ++w) tot += wsum[w];
        hpart[s * HB + b] = tot;
    }
}

__global__ void headscan(const unsigned* __restrict__ hpart, unsigned* __restrict__ hbase,
                         unsigned* __restrict__ nu, unsigned* __restrict__ start)
{   // 1 block, 64 threads; t<2 do serial scans (96 elems each)
    int t = threadIdx.x;
    if (t < Bn) {
        unsigned run = 0;
        for (int b = 0; b < HB; ++b) { hbase[t * HB + b] = run; run += hpart[t * HB + b]; }
        nu[t] = run;
        start[(size_t)t * (Vv + 1) + run] = (unsigned)Vv;  // start[nu] = V
    }
}

__global__ void ranks(const unsigned* __restrict__ skeys, const unsigned* __restrict__ hbase,
                      unsigned* __restrict__ start)
{   // grid: B*HB, 512 threads
    int blk = blockIdx.x;
    int s = blk / HB, b = blk % HB;
    int i = b * 512 + threadIdx.x;
    size_t base = (size_t)s * Vv;
    unsigned k = skeys[base + i];
    bool head = (i == 0) || (skeys[base + i - 1] != k);
    unsigned long long bal = __ballot(head);
    int lane = threadIdx.x & 63, wid = threadIdx.x >> 6;
    __shared__ unsigned wsum[8];
    if (lane == 0) wsum[wid] = (unsigned)__popcll(bal);
    __syncthreads();
    unsigned wbase = 0;
    for (int w = 0; w < wid; ++w) wbase += wsum[w];
    unsigned lpre = (unsigned)__popcll(bal & ((1ull << lane) - 1ull));
    if (head) {
        unsigned r = hbase[s * HB + b] + wbase + lpre;
        start[(size_t)s * (Vv + 1) + r] = (unsigned)i;
    }
}

// ---------------- output build ----------------
__global__ void outputk(const unsigned* __restrict__ sidx, const unsigned* __restrict__ start,
                        const unsigned* __restrict__ nu, const int* __restrict__ indb,
                        const float* __restrict__ coor, const float* __restrict__ featb,
                        float* __restrict__ out)
{   // grid: B*V blocks, 128 threads; block = one output row u
    int blk = blockIdx.x;
    int s = blk / Vv, u = blk % Vv;
    int t = threadIdx.x;
    size_t su = (size_t)s * Vv + u;
    unsigned n_u = nu[s];
    __shared__ unsigned src[4];
    bool valid = (u < (int)n_u);   // block-uniform
    if (valid) {
        if (t < 4) {
            unsigned i0 = start[(size_t)s * (Vv + 1) + u];
            unsigned i1 = start[(size_t)s * (Vv + 1) + u + 1];
            unsigned c = i1 - i0;
            src[t] = sidx[(size_t)s * Vv + i0 + ((unsigned)t % c)];
        }
        __syncthreads();
        if (t < 3)
            out[IND0 + su * 3 + t] = (float)indb[((size_t)s * Vv + src[0]) * 3 + t];
        if (t < 12) {
            int j = t / 3, k = t % 3;
            out[COOR0 + (su * 4 + j) * 3 + k] = coor[((size_t)s * Vv + src[j]) * 3 + k];
        }
        #pragma unroll
        for (int j = 0; j < 4; ++j) {
            unsigned nsrc = src[j] / 3;
            out[FEAT0 + (su * 4 + j) * Cc + t] = featb[((size_t)s * Nn + nsrc) * Cc + t];
        }
        if (t == 0) out[MASK0 + su] = 1.0f;
    } else {
        __syncthreads();
        if (t < 3)  out[IND0 + su * 3 + t] = 0.f;
        if (t < 12) out[COOR0 + su * 12 + t] = 0.f;
        #pragma unroll
        for (int j = 0; j < 4; ++j) out[FEAT0 + (su * 4 + j) * Cc + t] = 0.f;
        if (t == 0) out[MASK0 + su] = 0.f;
    }
}

// ---------------- host launch ----------------
extern "C" void kernel_launch(void* const* d_in, const int* in_sizes, int n_in,
                              void* d_out, int out_size, void* d_ws, size_t ws_size,
                              hipStream_t stream)
{
    const int*   ID  = (const int*)d_in[0];
    const float* CO  = (const float*)d_in[1];
    const float* FT  = (const float*)d_in[2];
    const float* W1  = (const float*)d_in[3];
    const float* b1  = (const float*)d_in[4];
    const float* g1  = (const float*)d_in[5];
    const float* be1 = (const float*)d_in[6];
    const float* W2  = (const float*)d_in[7];
    const float* b2  = (const float*)d_in[8];
    const float* g2  = (const float*)d_in[9];
    const float* be2 = (const float*)d_in[10];
    const float* W3  = (const float*)d_in[11];
    const float* b3  = (const float*)d_in[12];
    float* out = (float*)d_out;

    char* wsc = (char*)d_ws;
    size_t off = 0;
    auto alloc = [&](size_t elems) -> void* {
        void* p = wsc + off;
        off += ((elems * 4 + 255) & ~(size_t)255);
        return p;
    };
    float*    H1    = (float*)alloc((size_t)Bn * Nn * Cc);
    float*    H2    = (float*)alloc((size_t)Bn * Nn * Cc);
    float*    LOGb  = (float*)alloc((size_t)Bn * Nn * M3);
    float*    PART  = (float*)alloc((size_t)Bn * 64 * 2 * Cc);
    float*    SS    = (float*)alloc((size_t)Bn * 2 * Cc);
    float*    COORb = (float*)alloc((size_t)Bn * Vv * 3);
    int*      INDB  = (int*)alloc((size_t)Bn * Vv * 3);
    float*    FEATB = (float*)alloc((size_t)Bn * Nn * Cc);
    unsigned* KA    = (unsigned*)alloc((size_t)Bn * Vv);
    unsigned* IA    = (unsigned*)alloc((size_t)Bn * Vv);
    unsigned* KB    = (unsigned*)alloc((size_t)Bn * Vv);
    unsigned* IB    = (unsigned*)alloc((size_t)Bn * Vv);
    unsigned* HIST  = (unsigned*)alloc((size_t)Bn * 1024 * NB);
    unsigned* BT    = (unsigned*)alloc((size_t)Bn * 1024);
    unsigned* BB    = (unsigned*)alloc((size_t)Bn * 1024);
    unsigned* HP    = (unsigned*)alloc((size_t)Bn * HB);
    unsigned* HO    = (unsigned*)alloc((size_t)Bn * HB);
    unsigned* NUp   = (unsigned*)alloc((size_t)Bn);
    unsigned* STp   = (unsigned*)alloc((size_t)Bn * (Vv + 1));
    (void)in_sizes; (void)n_in; (void)out_size; (void)ws_size;

    // MLP layer 1
    gemm_k128<<<Bn * 256 * 2, 256, 0, stream>>>(FT, W1, b1, H1, Cc, Cc, 256, 2);
    colstats<<<Bn * 64, 128, 0, stream>>>(H1, PART);
    bnfinalize<<<Bn, 128, 0, stream>>>(PART, g1, be1, SS);
    bnrelu<<<(Bn * Nn * Cc / 4) / 256, 256, 0, stream>>>(H1, SS, H1);
    // MLP layer 2
    gemm_k128<<<Bn * 256 * 2, 256, 0, stream>>>(H1, W2, b2, H2, Cc, Cc, 256, 2);
    colstats<<<Bn * 64, 128, 0, stream>>>(H2, PART);
    bnfinalize<<<Bn, 128, 0, stream>>>(PART, g2, be2, SS);
    bnrelu<<<(Bn * Nn * Cc / 4) / 256, 256, 0, stream>>>(H2, SS, H2);
    // layer 3 (logits, M=393)
    gemm_k128<<<Bn * 256 * 7, 256, 0, stream>>>(H2, W3, b3, LOGb, M3, M3, 256, 7);
    // votes
    prep<<<Bn * Nn, 128, 0, stream>>>(LOGb, FT, CO, ID, COORb, INDB, FEATB, KA, IA);
    // radix sort: 3 x 10-bit LSD passes (keys < 2^30)
    unsigned *kin = KA, *iin = IA, *kout = KB, *iout = IB;
    for (int p = 0; p < 3; ++p) {
        int shift = p * 10;
        rhist<<<Bn * NB, 256, 0, stream>>>(kin, HIST, shift);
        rscan1<<<Bn * 4, 256, 0, stream>>>(HIST, BT);
        rscan2<<<Bn, 1024, 0, stream>>>(BT, BB);
        rscatter<<<Bn * NB, 256, 0, stream>>>(kin, iin, kout, iout, HIST, BB, shift);
        unsigned* tk = kin; kin = kout; kout = tk;
        unsigned* ti = iin; iin = iout; iout = ti;
    }
    // grouping
    heads<<<Bn * HB, 512, 0, stream>>>(kin, HP);
    headscan<<<1, 64, 0, stream>>>(HP, HO, NUp, STp);
    ranks<<<Bn * HB, 512, 0, stream>>>(kin, HO, STp);
    // output
    outputk<<<Bn * Vv, 128, 0, stream>>>(iin, STp, NUp, INDB, COORb, FEATB, out);
}

// Round 2
// 252.880 us; speedup vs baseline: 1.2650x; 1.2650x over previous
//
#include <hip/hip_runtime.h>

constexpr int Bn = 2;
constexpr int Nn = 16384;
constexpr int Cc = 128;
constexpr int VFh = 3;
constexpr int Vv = Nn * VFh;        // 49152
constexpr int Pp = 4;
constexpr int LDc = 144;            // compact logits stride: 9 off3 + 128 feat + 7 pad
constexpr int SB = 96;              // sort blocks per sample (512 elems each)

// out layout (flat float32, reference return order)
constexpr size_t IND0  = 0;
constexpr size_t COOR0 = (size_t)Bn * Vv * 3;
constexpr size_t FEAT0 = COOR0 + (size_t)Bn * Vv * Pp * 3;
constexpr size_t MASK0 = FEAT0 + (size_t)Bn * Vv * Pp * Cc;

// ---------------- GEMM: out[n][col] = sum_k A[n][k]*W[map(col)][k] + bias[map(col)] ----
// 64x(JMAX*16) tile, 256 thr, micro 4xJMAX, BK=32. A stride fixed Cc=128.
// BN: apply bnrelu (scale/shift from ss) to A elements at load (bit-identical fmaf+fmaxf).
// COMPACT (layer3): only the 137 used columns of W3: col<9 -> W3 row (col/3)*131+col%3
// (off3 slots), col in [9,137) -> W3 row col+256 (feat_off channels).
template<int JMAX, bool BN, bool COMPACT>
__global__ __launch_bounds__(256) void gemm_t(
    const float* __restrict__ A, const float* __restrict__ W,
    const float* __restrict__ bias, const float* __restrict__ ss,
    float* __restrict__ out, int ldo, int nRB)
{
    constexpr int BNT = JMAX * 16;
    __shared__ float As[64 * 36];
    __shared__ float Ws[BNT * 36];

    int bid = blockIdx.x;
    int s = bid / nRB, rb = bid % nRB;
    const float* Ag = A + (size_t)s * Nn * Cc + (size_t)rb * 64 * Cc;
    float* outg = out + (size_t)s * Nn * ldo + (size_t)rb * 64 * ldo;
    const float* sp = nullptr;
    if constexpr (BN) sp = ss + (size_t)s * 2 * Cc;

    int t = threadIdx.x, tx = t & 15, ty = t >> 4;

    float acc[4][JMAX];
    #pragma unroll
    for (int i = 0; i < 4; ++i)
        #pragma unroll
        for (int j = 0; j < JMAX; ++j) acc[i][j] = 0.f;

    for (int stage = 0; stage < 4; ++stage) {
        int k0 = stage * 32;
        if (stage) __syncthreads();
        // stage A: 64 rows x 32 k = 512 float4
        #pragma unroll
        for (int r = 0; r < 2; ++r) {
            int idx = r * 256 + t;
            int row = idx >> 3, c4 = (idx & 7) * 4;
            float4 v = *(const float4*)(Ag + (size_t)row * Cc + k0 + c4);
            if constexpr (BN) {
                int ch = k0 + c4;
                v.x = fmaxf(0.f, fmaf(v.x, sp[ch + 0], sp[Cc + ch + 0]));
                v.y = fmaxf(0.f, fmaf(v.y, sp[ch + 1], sp[Cc + ch + 1]));
                v.z = fmaxf(0.f, fmaf(v.z, sp[ch + 2], sp[Cc + ch + 2]));
                v.w = fmaxf(0.f, fmaf(v.w, sp[ch + 3], sp[Cc + ch + 3]));
            }
            *(float4*)&As[row * 36 + c4] = v;
        }
        // stage W: BNT rows x 32 k
        for (int idx = t; idx < BNT * 8; idx += 256) {
            int row = idx >> 3, c4 = (idx & 7) * 4;
            float4 v = make_float4(0.f, 0.f, 0.f, 0.f);
            bool ok = true;
            if constexpr (COMPACT) ok = (row < 137);
            if (ok) {
                int wr = row;
                if constexpr (COMPACT) wr = (row < 9) ? (row / 3) * 131 + (row % 3) : row + 256;
                v = *(const float4*)(W + (size_t)wr * Cc + k0 + c4);
            }
            *(float4*)&Ws[row * 36 + c4] = v;
        }
        __syncthreads();
        #pragma unroll
        for (int k4 = 0; k4 < 8; ++k4) {
            int k = k4 * 4;
            float4 av[4];
            #pragma unroll
            for (int i = 0; i < 4; ++i) av[i] = *(const float4*)&As[(i * 16 + ty) * 36 + k];
            #pragma unroll
            for (int j = 0; j < JMAX; ++j) {
                float4 wv = *(const float4*)&Ws[(j * 16 + tx) * 36 + k];
                #pragma unroll
                for (int i = 0; i < 4; ++i) {
                    float a0 = acc[i][j];
                    a0 = fmaf(av[i].x, wv.x, a0);
                    a0 = fmaf(av[i].y, wv.y, a0);
                    a0 = fmaf(av[i].z, wv.z, a0);
                    a0 = fmaf(av[i].w, wv.w, a0);
                    acc[i][j] = a0;
                }
            }
        }
    }
    #pragma unroll
    for (int j = 0; j < JMAX; ++j) {
        int col = j * 16 + tx;
        bool ok = true;
        if constexpr (COMPACT) ok = (col < 137);
        if (ok) {
            int br = col;
            if constexpr (COMPACT) br = (col < 9) ? (col / 3) * 131 + (col % 3) : col + 256;
            float bv = bias[br];
            #pragma unroll
            for (int i = 0; i < 4; ++i)
                outg[(size_t)(i * 16 + ty) * ldo + col] = acc[i][j] + bv;
        }
    }
}

// ---------------- deterministic column stats (byte-identical to R1) ----------------
__global__ void colstats(const float* __restrict__ Y, float* __restrict__ part)
{   // grid: B*64 blocks, 128 threads; 256 rows per block
    int blk = blockIdx.x;
    int s = blk >> 6, b = blk & 63;
    const float* Yp = Y + (size_t)s * Nn * Cc + (size_t)b * 256 * Cc;
    int c = threadIdx.x;
    float sm = 0.f, sq = 0.f;
    for (int r = 0; r < 256; ++r) {
        float v = Yp[(size_t)r * Cc + c];
        sm += v; sq += v * v;
    }
    float* pp = part + ((size_t)s * 64 + b) * 2 * Cc;
    pp[c] = sm;
    pp[Cc + c] = sq;
}

__global__ void bnfinalize(const float* __restrict__ part, const float* __restrict__ g,
                           const float* __restrict__ be, float* __restrict__ ss)
{
    int s = blockIdx.x, c = threadIdx.x;
    const float* pp = part + (size_t)s * 64 * 2 * Cc;
    float sm = 0.f, sq = 0.f;
    for (int b = 0; b < 64; ++b) {
        sm += pp[(size_t)b * 2 * Cc + c];
        sq += pp[(size_t)b * 2 * Cc + Cc + c];
    }
    float m   = sm / (float)Nn;
    float var = sq / (float)Nn - m * m;
    float inv = 1.0f / sqrtf(var + 1e-5f);
    float sc  = g[c] * inv;
    ss[(size_t)s * 2 * Cc + c]      = sc;
    ss[(size_t)s * 2 * Cc + Cc + c] = be[c] - m * sc;
}

// ---------------- zero pass-0 hist ----------------
__global__ void zerok(uint4* __restrict__ p)
{
    p[(size_t)blockIdx.x * 256 + threadIdx.x] = make_uint4(0, 0, 0, 0);
}

// ---------------- vote prep: coor / ind / keys / feat_base / pass-0 hist -----------
__global__ void prep(const float* __restrict__ LOGc, const float* __restrict__ FT,
                     const float* __restrict__ CO, const int* __restrict__ ID,
                     float* __restrict__ coor, int* __restrict__ indb,
                     float* __restrict__ featb, unsigned* __restrict__ keys,
                     unsigned* __restrict__ idx0, unsigned* __restrict__ histA)
{   // grid: B*N blocks, 128 threads
    int blk = blockIdx.x;
    int s = blk >> 14, n = blk & 16383;
    const float* Lr = LOGc + ((size_t)s * Nn + n) * LDc;
    int t = threadIdx.x;
    featb[((size_t)s * Nn + n) * Cc + t] =
        FT[((size_t)s * Nn + n) * Cc + t] + Lr[9 + t];
    if (t < 3) {
        int j = t;
        float o0 = Lr[j * 3 + 0], o1 = Lr[j * 3 + 1], o2 = Lr[j * 3 + 2];
        int v = n * 3 + j;
        size_t vb = (size_t)s * Vv + v;
        const float* co = CO + ((size_t)s * Nn + n) * 3;
        coor[vb * 3 + 0] = co[0] + o0;
        coor[vb * 3 + 1] = co[1] + o1;
        coor[vb * 3 + 2] = co[2] + o2;
        const int* id = ID + ((size_t)s * Nn + n) * 3;
        int gi0 = (int)(o0 / 0.1f), gi1 = (int)(o1 / 0.1f), gi2 = (int)(o2 / 0.1f);
        int i0 = id[0] + gi0, i1 = id[1] + gi1, i2 = id[2] + gi2;
        indb[vb * 3 + 0] = i0; indb[vb * 3 + 1] = i1; indb[vb * 3 + 2] = i2;
        int h0 = min(max(i0, -512), 511) + 512;
        int h1 = min(max(i1, -512), 511) + 512;
        int h2 = min(max(i2, -512), 511) + 512;
        unsigned key = ((unsigned)h0 * 1024u + (unsigned)h1) * 1024u + (unsigned)h2;
        keys[vb] = key;
        idx0[vb] = (unsigned)v;
        atomicAdd(&histA[(size_t)s * SB * 1024 + (size_t)(v >> 9) * 1024 + (key & 1023u)], 1u);
    }
}

// ---------------- merged radix scan: per-bin block-prefix + bin base; zero other ----
__global__ __launch_bounds__(1024) void scank(unsigned* __restrict__ h,
                                              unsigned* __restrict__ other,
                                              unsigned* __restrict__ BB, int zeroOther)
{   // grid: Bn blocks, 1024 threads; layout h[b*1024+d]
    int s = blockIdx.x, d = threadIdx.x;
    unsigned* hp = h + (size_t)s * SB * 1024;
    unsigned run = 0;
    for (int b = 0; b < SB; ++b) {
        unsigned v = hp[(size_t)b * 1024 + d];
        hp[(size_t)b * 1024 + d] = run;
        run += v;
    }
    __shared__ unsigned sh[1024];
    sh[d] = run;
    __syncthreads();
    for (int off = 1; off < 1024; off <<= 1) {
        unsigned add = (d >= off) ? sh[d - off] : 0u;
        __syncthreads();
        sh[d] += add;
        __syncthreads();
    }
    BB[s * 1024 + d] = sh[d] - run;
    if (zeroOther) {
        unsigned* op = other + (size_t)s * SB * 1024;
        for (int b = 0; b < SB; ++b) op[(size_t)b * 1024 + d] = 0u;
    }
}

// ---------------- stable scatter + next-pass hist ----------------
template<int PASS>
__global__ __launch_bounds__(512) void scatterk(
    const unsigned* __restrict__ kIn, const unsigned* __restrict__ iIn,
    unsigned* __restrict__ kOut, unsigned* __restrict__ iOut,
    const unsigned* __restrict__ hpref, const unsigned* __restrict__ BB,
    unsigned* __restrict__ nextH)
{   // grid: Bn*SB, 512 threads
    __shared__ unsigned hl[1024];
    int t = threadIdx.x;
    hl[t] = 0u; hl[512 + t] = 0u;
    __syncthreads();
    int blk = blockIdx.x;
    int s = blk / SB, b = blk % SB;
    size_t base = (size_t)s * Vv + (size_t)b * 512 + t;
    unsigned key = kIn[base], idx = iIn[base];
    unsigned d = (key >> (PASS * 10)) & 1023u;
    unsigned long long m = ~0ull;
    #pragma unroll
    for (int bit = 0; bit < 10; ++bit) {
        bool bb = (d >> bit) & 1u;
        unsigned long long bal = __ballot(bb);
        m &= bb ? bal : ~bal;
    }
    int lane = t & 63, wid = t >> 6;
    int lanesBelow = __popcll(m & ((1ull << lane) - 1ull));
    int cnt = __popcll(m);
    int leader = __ffsll((unsigned long long)m) - 1;
    unsigned basec = 0;
    for (int w = 0; w < 8; ++w) {
        if (wid == w) {
            basec = hl[d];
            if (lane == leader) hl[d] = basec + (unsigned)cnt;
        }
        __syncthreads();
    }
    unsigned dest = BB[s * 1024 + (int)d]
                  + hpref[(size_t)s * SB * 1024 + (size_t)b * 1024 + d]
                  + basec + (unsigned)lanesBelow;
    kOut[(size_t)s * Vv + dest] = key;
    iOut[(size_t)s * Vv + dest] = idx;
    if constexpr (PASS < 2) {
        unsigned d2 = (key >> ((PASS + 1) * 10)) & 1023u;
        atomicAdd(&nextH[(size_t)s * SB * 1024 + (size_t)(dest >> 9) * 1024 + d2], 1u);
    }
}

// ---------------- group heads (per-block counts) ----------------
__global__ __launch_bounds__(512) void headsct(const unsigned* __restrict__ skeys,
                                               unsigned* __restrict__ hpart)
{   // grid: B*SB, 512 threads
    int blk = blockIdx.x;
    int s = blk / SB, b = blk % SB;
    int i = b * 512 + threadIdx.x;
    size_t base = (size_t)s * Vv;
    unsigned k = skeys[base + i];
    bool head = (i == 0) || (skeys[base + i - 1] != k);
    __shared__ unsigned wsum[8];
    unsigned long long bal = __ballot(head);
    int lane = threadIdx.x & 63, wid = threadIdx.x >> 6;
    if (lane == 0) wsum[wid] = (unsigned)__popcll(bal);
    __syncthreads();
    if (threadIdx.x == 0) {
        unsigned tot = 0;
        for (int w = 0; w < 8; ++w) tot += wsum[w];
        hpart[s * SB + b] = tot;
    }
}

// ---------------- ranks: self-prefix over hpart + write group starts ----------------
__global__ __launch_bounds__(512) void ranksk(const unsigned* __restrict__ skeys,
                                              const unsigned* __restrict__ hpart,
                                              unsigned* __restrict__ start,
                                              unsigned* __restrict__ nu)
{   // grid: B*SB, 512 threads
    int blk = blockIdx.x;
    int s = blk / SB, b = blk % SB;
    int t = threadIdx.x;
    __shared__ unsigned hp[SB];
    __shared__ unsigned pre[SB + 1];
    if (t < SB) hp[t] = hpart[s * SB + t];
    __syncthreads();
    if (t == 0) {
        unsigned run = 0;
        for (int i = 0; i < SB; ++i) { pre[i] = run; run += hp[i]; }
        pre[SB] = run;
    }
    __syncthreads();
    int i = b * 512 + t;
    size_t base = (size_t)s * Vv;
    unsigned k = skeys[base + i];
    bool head = (i == 0) || (skeys[base + i - 1] != k);
    unsigned long long bal = __ballot(head);
    int lane = t & 63, wid = t >> 6;
    __shared__ unsigned wsum[8];
    if (lane == 0) wsum[wid] = (unsigned)__popcll(bal);
    __syncthreads();
    unsigned wbase = 0;
    for (int w = 0; w < wid; ++w) wbase += wsum[w];
    unsigned lpre = (unsigned)__popcll(bal & ((1ull << lane) - 1ull));
    if (head)
        start[(size_t)s * (Vv + 1) + pre[b] + wbase + lpre] = (unsigned)i;
    if (b == 0 && t == 0) {
        nu[s] = pre[SB];
        start[(size_t)s * (Vv + 1) + pre[SB]] = (unsigned)Vv;
    }
}

// ---------------- output build: 1 wave per output row, float4 feat ----------------
__global__ __launch_bounds__(256) void outputk(
    const unsigned* __restrict__ sidx, const unsigned* __restrict__ start,
    const unsigned* __restrict__ nu, const int* __restrict__ indb,
    const float* __restrict__ coor, const float* __restrict__ featb,
    float* __restrict__ out)
{   // grid: B*V/4 blocks, 256 threads (4 waves, 1 row each)
    int wid = threadIdx.x >> 6, lane = threadIdx.x & 63;
    int g = blockIdx.x * 4 + wid;
    int s = g / Vv, u = g - s * Vv;
    size_t su = (size_t)s * Vv + u;
    bool valid = (unsigned)u < nu[s];
    float4* out4 = (float4*)out;
    int f = lane & 31, jlo = lane >> 5;
    if (valid) {
        const unsigned* st = start + (size_t)s * (Vv + 1);
        unsigned i0 = st[u], i1 = st[u + 1];
        unsigned c = i1 - i0;
        unsigned my = sidx[(size_t)s * Vv + i0 + ((unsigned)(lane & 3)) % c];
        unsigned sv[4];
        sv[0] = __shfl(my, 0); sv[1] = __shfl(my, 1);
        sv[2] = __shfl(my, 2); sv[3] = __shfl(my, 3);
        const float4* fb = (const float4*)(featb + (size_t)s * Nn * Cc);
        #pragma unroll
        for (int h = 0; h < 2; ++h) {
            int j = jlo + 2 * h;
            out4[(FEAT0 >> 2) + su * 128 + (size_t)j * 32 + f] =
                fb[(size_t)(sv[j] / 3) * 32 + f];
        }
        if (lane < 12)
            out[COOR0 + su * 12 + lane] =
                coor[((size_t)s * Vv + sv[lane / 3]) * 3 + lane % 3];
        else if (lane < 15)
            out[IND0 + su * 3 + (lane - 12)] =
                (float)indb[((size_t)s * Vv + sv[0]) * 3 + (lane - 12)];
        else if (lane == 15)
            out[MASK0 + su] = 1.f;
    } else {
        float4 z = make_float4(0.f, 0.f, 0.f, 0.f);
        #pragma unroll
        for (int h = 0; h < 2; ++h)
            out4[(FEAT0 >> 2) + su * 128 + (size_t)(jlo + 2 * h) * 32 + f] = z;
        if (lane < 12)       out[COOR0 + su * 12 + lane] = 0.f;
        else if (lane < 15)  out[IND0 + su * 3 + (lane - 12)] = 0.f;
        else if (lane == 15) out[MASK0 + su] = 0.f;
    }
}

// ---------------- host launch ----------------
extern "C" void kernel_launch(void* const* d_in, const int* in_sizes, int n_in,
                              void* d_out, int out_size, void* d_ws, size_t ws_size,
                              hipStream_t stream)
{
    const int*   ID  = (const int*)d_in[0];
    const float* CO  = (const float*)d_in[1];
    const float* FT  = (const float*)d_in[2];
    const float* W1  = (const float*)d_in[3];
    const float* b1  = (const float*)d_in[4];
    const float* g1  = (const float*)d_in[5];
    const float* be1 = (const float*)d_in[6];
    const float* W2  = (const float*)d_in[7];
    const float* b2  = (const float*)d_in[8];
    const float* g2  = (const float*)d_in[9];
    const float* be2 = (const float*)d_in[10];
    const float* W3  = (const float*)d_in[11];
    const float* b3  = (const float*)d_in[12];
    float* out = (float*)d_out;

    char* wsc = (char*)d_ws;
    size_t off = 0;
    auto alloc = [&](size_t elems) -> void* {
        void* p = wsc + off;
        off += ((elems * 4 + 255) & ~(size_t)255);
        return p;
    };
    float*    H1    = (float*)alloc((size_t)Bn * Nn * Cc);
    float*    H2    = (float*)alloc((size_t)Bn * Nn * Cc);
    float*    LOGc  = (float*)alloc((size_t)Bn * Nn * LDc);
    float*    PART  = (float*)alloc((size_t)Bn * 64 * 2 * Cc);
    float*    SS    = (float*)alloc((size_t)Bn * 2 * Cc);
    float*    COORb = (float*)alloc((size_t)Bn * Vv * 3);
    int*      INDB  = (int*)alloc((size_t)Bn * Vv * 3);
    float*    FEATB = (float*)alloc((size_t)Bn * Nn * Cc);
    unsigned* KA    = (unsigned*)alloc((size_t)Bn * Vv);
    unsigned* IA    = (unsigned*)alloc((size_t)Bn * Vv);
    unsigned* KB    = (unsigned*)alloc((size_t)Bn * Vv);
    unsigned* IB    = (unsigned*)alloc((size_t)Bn * Vv);
    unsigned* HA    = (unsigned*)alloc((size_t)Bn * SB * 1024);
    unsigned* HB    = (unsigned*)alloc((size_t)Bn * SB * 1024);
    unsigned* BBuf  = (unsigned*)alloc((size_t)Bn * 1024);
    unsigned* HP    = (unsigned*)alloc((size_t)Bn * SB);
    unsigned* NUp   = (unsigned*)alloc((size_t)Bn);
    unsigned* STp   = (unsigned*)alloc((size_t)Bn * (Vv + 1));
    (void)in_sizes; (void)n_in; (void)out_size; (void)ws_size;

    // zero pass-0 hist (Bn*SB*1024 u32 = 49152 uint4)
    zerok<<<192, 256, 0, stream>>>((uint4*)HA);

    // MLP (BN fused into next layer's A-load; stats byte-identical to R1)
    gemm_t<8, false, false><<<Bn * 256, 256, 0, stream>>>(FT, W1, b1, nullptr, H1, Cc, 256);
    colstats<<<Bn * 64, 128, 0, stream>>>(H1, PART);
    bnfinalize<<<Bn, 128, 0, stream>>>(PART, g1, be1, SS);
    gemm_t<8, true, false><<<Bn * 256, 256, 0, stream>>>(H1, W2, b2, SS, H2, Cc, 256);
    colstats<<<Bn * 64, 128, 0, stream>>>(H2, PART);
    bnfinalize<<<Bn, 128, 0, stream>>>(PART, g2, be2, SS);
    gemm_t<9, true, true><<<Bn * 256, 256, 0, stream>>>(H2, W3, b3, SS, LOGc, LDc, 256);

    // votes (+ pass-0 hist)
    prep<<<Bn * Nn, 128, 0, stream>>>(LOGc, FT, CO, ID, COORb, INDB, FEATB, KA, IA, HA);

    // radix sort: 3 x 10-bit, fused hist, merged scans
    scank<<<Bn, 1024, 0, stream>>>(HA, HB, BBuf, 1);
    scatterk<0><<<Bn * SB, 512, 0, stream>>>(KA, IA, KB, IB, HA, BBuf, HB);
    scank<<<Bn, 1024, 0, stream>>>(HB, HA, BBuf, 1);
    scatterk<1><<<Bn * SB, 512, 0, stream>>>(KB, IB, KA, IA, HB, BBuf, HA);
    scank<<<Bn, 1024, 0, stream>>>(HA, HB, BBuf, 0);
    scatterk<2><<<Bn * SB, 512, 0, stream>>>(KA, IA, KB, IB, HA, BBuf, nullptr);

    // grouping
    headsct<<<Bn * SB, 512, 0, stream>>>(KB, HP);
    ranksk<<<Bn * SB, 512, 0, stream>>>(KB, HP, STp, NUp);

    // output
    outputk<<<Bn * Vv / 4, 256, 0, stream>>>(IB, STp, NUp, INDB, COORb, FEATB, out);
}

// Round 3
// 213.148 us; speedup vs baseline: 1.5008x; 1.1864x over previous
//
#include <hip/hip_runtime.h>

constexpr int Bn = 2;
constexpr int Nn = 16384;
constexpr int Cc = 128;
constexpr int Vv = Nn * 3;          // 49152
constexpr int Pp = 4;
constexpr int SB = 48;              // sort blocks per sample (1024 elems each)
constexpr int HB = 96;              // head/rank blocks per sample (512 elems each)

// out layout (flat float32, reference return order)
constexpr size_t IND0  = 0;
constexpr size_t COOR0 = (size_t)Bn * Vv * 3;
constexpr size_t FEAT0 = COOR0 + (size_t)Bn * Vv * Pp * 3;
constexpr size_t MASK0 = FEAT0 + (size_t)Bn * Vv * Pp * Cc;

// ---------------- GEMM layers 1/2: 64x128 tile, BK=32, micro 4x8 ----------------
template<bool BN>
__global__ __launch_bounds__(256) void gemm_t(
    const float* __restrict__ A, const float* __restrict__ W,
    const float* __restrict__ bias, const float* __restrict__ ss,
    float* __restrict__ out)
{
    __shared__ float As[64 * 36];
    __shared__ float Ws[128 * 36];

    int bid = blockIdx.x;
    int s = bid >> 8, rb = bid & 255;
    const float* Ag = A + (size_t)s * Nn * Cc + (size_t)rb * 64 * Cc;
    float* outg = out + (size_t)s * Nn * Cc + (size_t)rb * 64 * Cc;
    const float* sp = nullptr;
    if constexpr (BN) sp = ss + (size_t)s * 2 * Cc;

    int t = threadIdx.x, tx = t & 15, ty = t >> 4;

    float acc[4][8];
    #pragma unroll
    for (int i = 0; i < 4; ++i)
        #pragma unroll
        for (int j = 0; j < 8; ++j) acc[i][j] = 0.f;

    for (int stage = 0; stage < 4; ++stage) {
        int k0 = stage * 32;
        if (stage) __syncthreads();
        #pragma unroll
        for (int r = 0; r < 2; ++r) {
            int idx = r * 256 + t;
            int row = idx >> 3, c4 = (idx & 7) * 4;
            float4 v = *(const float4*)(Ag + (size_t)row * Cc + k0 + c4);
            if constexpr (BN) {
                int ch = k0 + c4;
                v.x = fmaxf(0.f, fmaf(v.x, sp[ch + 0], sp[Cc + ch + 0]));
                v.y = fmaxf(0.f, fmaf(v.y, sp[ch + 1], sp[Cc + ch + 1]));
                v.z = fmaxf(0.f, fmaf(v.z, sp[ch + 2], sp[Cc + ch + 2]));
                v.w = fmaxf(0.f, fmaf(v.w, sp[ch + 3], sp[Cc + ch + 3]));
            }
            *(float4*)&As[row * 36 + c4] = v;
        }
        #pragma unroll
        for (int r = 0; r < 4; ++r) {
            int idx = r * 256 + t;
            int row = idx >> 3, c4 = (idx & 7) * 4;
            *(float4*)&Ws[row * 36 + c4] = *(const float4*)(W + (size_t)row * Cc + k0 + c4);
        }
        __syncthreads();
        #pragma unroll
        for (int k4 = 0; k4 < 8; ++k4) {
            int k = k4 * 4;
            float4 av[4];
            #pragma unroll
            for (int i = 0; i < 4; ++i) av[i] = *(const float4*)&As[(i * 16 + ty) * 36 + k];
            #pragma unroll
            for (int j = 0; j < 8; ++j) {
                float4 wv = *(const float4*)&Ws[(j * 16 + tx) * 36 + k];
                #pragma unroll
                for (int i = 0; i < 4; ++i) {
                    float a0 = acc[i][j];
                    a0 = fmaf(av[i].x, wv.x, a0);
                    a0 = fmaf(av[i].y, wv.y, a0);
                    a0 = fmaf(av[i].z, wv.z, a0);
                    a0 = fmaf(av[i].w, wv.w, a0);
                    acc[i][j] = a0;
                }
            }
        }
    }
    #pragma unroll
    for (int j = 0; j < 8; ++j) {
        int col = j * 16 + tx;
        float bv = bias[col];
        #pragma unroll
        for (int i = 0; i < 4; ++i)
            outg[(size_t)(i * 16 + ty) * Cc + col] = acc[i][j] + bv;
    }
}

// ---------------- GEMM layer 3 + fused vote prep ----------------
// Compact 137 cols: col<9 -> W3 row (col/3)*131+col%3 ; col in [9,137) -> row col+256.
__global__ __launch_bounds__(256) void gemm3_fused(
    const float* __restrict__ A, const float* __restrict__ W,
    const float* __restrict__ bias, const float* __restrict__ ss,
    const float* __restrict__ FT, const float* __restrict__ CO,
    const int* __restrict__ ID,
    float* __restrict__ featb, float* __restrict__ coor,
    int* __restrict__ indb, unsigned* __restrict__ keys,
    unsigned* __restrict__ idx0, unsigned* __restrict__ hist0)
{
    __shared__ float As[64 * 36];
    __shared__ float Ws[144 * 36];

    int bid = blockIdx.x;
    int s = bid >> 8, rb = bid & 255;
    const float* Ag = A + (size_t)s * Nn * Cc + (size_t)rb * 64 * Cc;
    const float* sp = ss + (size_t)s * 2 * Cc;

    int t = threadIdx.x, tx = t & 15, ty = t >> 4;

    float acc[4][9];
    #pragma unroll
    for (int i = 0; i < 4; ++i)
        #pragma unroll
        for (int j = 0; j < 9; ++j) acc[i][j] = 0.f;

    for (int stage = 0; stage < 4; ++stage) {
        int k0 = stage * 32;
        if (stage) __syncthreads();
        #pragma unroll
        for (int r = 0; r < 2; ++r) {
            int idx = r * 256 + t;
            int row = idx >> 3, c4 = (idx & 7) * 4;
            float4 v = *(const float4*)(Ag + (size_t)row * Cc + k0 + c4);
            int ch = k0 + c4;
            v.x = fmaxf(0.f, fmaf(v.x, sp[ch + 0], sp[Cc + ch + 0]));
            v.y = fmaxf(0.f, fmaf(v.y, sp[ch + 1], sp[Cc + ch + 1]));
            v.z = fmaxf(0.f, fmaf(v.z, sp[ch + 2], sp[Cc + ch + 2]));
            v.w = fmaxf(0.f, fmaf(v.w, sp[ch + 3], sp[Cc + ch + 3]));
            *(float4*)&As[row * 36 + c4] = v;
        }
        for (int idx = t; idx < 144 * 8; idx += 256) {
            int row = idx >> 3, c4 = (idx & 7) * 4;
            float4 v = make_float4(0.f, 0.f, 0.f, 0.f);
            if (row < 137) {
                int wr = (row < 9) ? (row / 3) * 131 + (row % 3) : row + 256;
                v = *(const float4*)(W + (size_t)wr * Cc + k0 + c4);
            }
            *(float4*)&Ws[row * 36 + c4] = v;
        }
        __syncthreads();
        #pragma unroll
        for (int k4 = 0; k4 < 8; ++k4) {
            int k = k4 * 4;
            float4 av[4];
            #pragma unroll
            for (int i = 0; i < 4; ++i) av[i] = *(const float4*)&As[(i * 16 + ty) * 36 + k];
            #pragma unroll
            for (int j = 0; j < 9; ++j) {
                float4 wv = *(const float4*)&Ws[(j * 16 + tx) * 36 + k];
                #pragma unroll
                for (int i = 0; i < 4; ++i) {
                    float a0 = acc[i][j];
                    a0 = fmaf(av[i].x, wv.x, a0);
                    a0 = fmaf(av[i].y, wv.y, a0);
                    a0 = fmaf(av[i].z, wv.z, a0);
                    a0 = fmaf(av[i].w, wv.w, a0);
                    acc[i][j] = a0;
                }
            }
        }
    }

    // ---------------- fused epilogue ----------------
    __syncthreads();                    // done with As/Ws reads
    __shared__ float L9[64 * 12];       // off3 logits (cols 0..8), +bias
    int n0 = rb * 64;
    const float* FTg = FT + ((size_t)s * Nn + n0) * Cc;
    float* FBg = featb + ((size_t)s * Nn + n0) * Cc;
    #pragma unroll
    for (int j = 0; j < 9; ++j) {
        int col = j * 16 + tx;
        if (col < 9) {
            float bv = bias[(col / 3) * 131 + col % 3];
            #pragma unroll
            for (int i = 0; i < 4; ++i)
                L9[(i * 16 + ty) * 12 + col] = acc[i][j] + bv;
        } else if (col < 137) {
            int ch = col - 9;
            float bv = bias[col + 256];
            #pragma unroll
            for (int i = 0; i < 4; ++i) {
                int row = i * 16 + ty;
                float lg = acc[i][j] + bv;                    // == old LOGc value
                FBg[(size_t)row * Cc + ch] = FTg[(size_t)row * Cc + ch] + lg;
            }
        }
    }
    __syncthreads();
    if (t < 192) {
        int row = t / 3, jv = t - row * 3;
        int n = n0 + row, v = n * 3 + jv;
        size_t vb = (size_t)s * Vv + v;
        float o0 = L9[row * 12 + jv * 3 + 0];
        float o1 = L9[row * 12 + jv * 3 + 1];
        float o2 = L9[row * 12 + jv * 3 + 2];
        const float* co = CO + ((size_t)s * Nn + n) * 3;
        coor[vb * 3 + 0] = co[0] + o0;
        coor[vb * 3 + 1] = co[1] + o1;
        coor[vb * 3 + 2] = co[2] + o2;
        const int* id = ID + ((size_t)s * Nn + n) * 3;
        int gi0 = (int)(o0 / 0.1f), gi1 = (int)(o1 / 0.1f), gi2 = (int)(o2 / 0.1f);
        int i0 = id[0] + gi0, i1 = id[1] + gi1, i2 = id[2] + gi2;
        indb[vb * 3 + 0] = i0; indb[vb * 3 + 1] = i1; indb[vb * 3 + 2] = i2;
        int h0 = min(max(i0, -512), 511) + 512;
        int h1 = min(max(i1, -512), 511) + 512;
        int h2 = min(max(i2, -512), 511) + 512;
        unsigned key = ((unsigned)h0 * 1024u + (unsigned)h1) * 1024u + (unsigned)h2;
        keys[vb] = key;
        idx0[vb] = (unsigned)v;
        atomicAdd(&hist0[(size_t)s * SB * 1024 + (size_t)(v >> 10) * 1024 + (key & 1023u)], 1u);
    }
}

// ---------------- deterministic column stats (byte-identical) ----------------
__global__ void colstats(const float* __restrict__ Y, float* __restrict__ part)
{
    int blk = blockIdx.x;
    int s = blk >> 6, b = blk & 63;
    const float* Yp = Y + (size_t)s * Nn * Cc + (size_t)b * 256 * Cc;
    int c = threadIdx.x;
    float sm = 0.f, sq = 0.f;
    for (int r = 0; r < 256; ++r) {
        float v = Yp[(size_t)r * Cc + c];
        sm += v; sq += v * v;
    }
    float* pp = part + ((size_t)s * 64 + b) * 2 * Cc;
    pp[c] = sm;
    pp[Cc + c] = sq;
}

__global__ void bnfinalize(const float* __restrict__ part, const float* __restrict__ g,
                           const float* __restrict__ be, float* __restrict__ ss)
{
    int s = blockIdx.x, c = threadIdx.x;
    const float* pp = part + (size_t)s * 64 * 2 * Cc;
    float sm = 0.f, sq = 0.f;
    for (int b = 0; b < 64; ++b) {
        sm += pp[(size_t)b * 2 * Cc + c];
        sq += pp[(size_t)b * 2 * Cc + Cc + c];
    }
    float m   = sm / (float)Nn;
    float var = sq / (float)Nn - m * m;
    float inv = 1.0f / sqrtf(var + 1e-5f);
    float sc  = g[c] * inv;
    ss[(size_t)s * 2 * Cc + c]      = sc;
    ss[(size_t)s * 2 * Cc + Cc + c] = be[c] - m * sc;
}

// ---------------- zero the 3 hist buffers ----------------
__global__ void zerok(uint4* __restrict__ p)
{
    p[(size_t)blockIdx.x * 256 + threadIdx.x] = make_uint4(0, 0, 0, 0);
}

// ---------------- fused scan + stable scatter (+ next-pass hist) ----------------
template<int PASS>
__global__ __launch_bounds__(512) void scat(
    const unsigned* __restrict__ kIn, const unsigned* __restrict__ iIn,
    unsigned* __restrict__ kOut, unsigned* __restrict__ iOut,
    const unsigned* __restrict__ hist, unsigned* __restrict__ nextH)
{   // grid: Bn*SB blocks, 512 threads, 1024 elems/block
    __shared__ unsigned hw[8 * 1024];   // per-wave digit counts -> exclusive wave offsets
    __shared__ unsigned tot[1024];      // digit totals -> binBase + my-block prefix
    int t = threadIdx.x, lane = t & 63, w = t >> 6;
    int blk = blockIdx.x, s = blk / SB, b = blk % SB;

    // wave-private zero of this wave's hw row (no sync needed: row is wave-private)
    #pragma unroll
    for (int i = 0; i < 16; ++i) hw[w * 1024 + i * 64 + lane] = 0u;

    // global hist scan: 2 digits/thread, block-prefix + totals
    const uint2* hs2 = (const uint2*)(hist + (size_t)s * SB * 1024);
    int d0 = 2 * t, d1 = 2 * t + 1;
    unsigned run0 = 0, run1 = 0, my0 = 0, my1 = 0;
    for (int bb = 0; bb < SB; ++bb) {
        uint2 v = hs2[bb * 512 + t];
        if (bb == b) { my0 = run0; my1 = run1; }
        run0 += v.x; run1 += v.y;
    }
    tot[d0] = run0; tot[d1] = run1;
    __syncthreads();
    for (int ofs = 1; ofs < 1024; ofs <<= 1) {
        unsigned a0 = (d0 >= ofs) ? tot[d0 - ofs] : 0u;
        unsigned a1 = (d1 >= ofs) ? tot[d1 - ofs] : 0u;
        __syncthreads();
        tot[d0] += a0; tot[d1] += a1;
        __syncthreads();
    }
    // tot[d] := binBase(exclusive over digits) + this block's prefix within digit
    tot[d0] = tot[d0] - run0 + my0;
    tot[d1] = tot[d1] - run1 + my1;

    // stable in-block ranking: wave chunks of 128, 2 slots of 64 (position order)
    size_t base = (size_t)s * Vv + (size_t)b * 1024;
    unsigned keyE[2], idxE[2], rkE[2], dE[2];
    #pragma unroll
    for (int e = 0; e < 2; ++e) {
        int pos = w * 128 + e * 64 + lane;
        keyE[e] = kIn[base + pos];
        idxE[e] = iIn[base + pos];
        unsigned d = (keyE[e] >> (PASS * 10)) & 1023u;
        dE[e] = d;
        unsigned long long m = ~0ull;
        #pragma unroll
        for (int bit = 0; bit < 10; ++bit) {
            bool bbit = (d >> bit) & 1u;
            unsigned long long bal = __ballot(bbit);
            m &= bbit ? bal : ~bal;
        }
        int lanesBelow = __popcll(m & ((1ull << lane) - 1ull));
        int cnt = __popcll(m);
        int leader = __ffsll((unsigned long long)m) - 1;
        unsigned basec = hw[w * 1024 + d];          // wave-lockstep read-before-write
        if (lane == leader) hw[w * 1024 + d] = basec + (unsigned)cnt;
        rkE[e] = basec + (unsigned)lanesBelow;
    }
    __syncthreads();
    // hw rows -> cross-wave exclusive offsets, in place (one thread per 2 digits)
    {
        unsigned r0 = 0, r1 = 0;
        for (int ww = 0; ww < 8; ++ww) {
            unsigned v0 = hw[ww * 1024 + d0], v1 = hw[ww * 1024 + d1];
            hw[ww * 1024 + d0] = r0; hw[ww * 1024 + d1] = r1;
            r0 += v0; r1 += v1;
        }
    }
    __syncthreads();
    #pragma unroll
    for (int e = 0; e < 2; ++e) {
        unsigned dest = tot[dE[e]] + hw[w * 1024 + dE[e]] + rkE[e];
        kOut[(size_t)s * Vv + dest] = keyE[e];
        iOut[(size_t)s * Vv + dest] = idxE[e];
        if constexpr (PASS < 2) {
            unsigned d2 = (keyE[e] >> ((PASS + 1) * 10)) & 1023u;
            atomicAdd(&nextH[(size_t)s * SB * 1024 + (size_t)(dest >> 10) * 1024 + d2], 1u);
        }
    }
}

// ---------------- group heads (per-block counts) ----------------
__global__ __launch_bounds__(512) void headsct(const unsigned* __restrict__ skeys,
                                               unsigned* __restrict__ hpart)
{
    int blk = blockIdx.x;
    int s = blk / HB, b = blk % HB;
    int i = b * 512 + threadIdx.x;
    size_t base = (size_t)s * Vv;
    unsigned k = skeys[base + i];
    bool head = (i == 0) || (skeys[base + i - 1] != k);
    __shared__ unsigned wsum[8];
    unsigned long long bal = __ballot(head);
    int lane = threadIdx.x & 63, wid = threadIdx.x >> 6;
    if (lane == 0) wsum[wid] = (unsigned)__popcll(bal);
    __syncthreads();
    if (threadIdx.x == 0) {
        unsigned tot = 0;
        for (int w = 0; w < 8; ++w) tot += wsum[w];
        hpart[s * HB + b] = tot;
    }
}

// ---------------- ranks: self-prefix over hpart + write group starts ----------------
__global__ __launch_bounds__(512) void ranksk(const unsigned* __restrict__ skeys,
                                              const unsigned* __restrict__ hpart,
                                              unsigned* __restrict__ start,
                                              unsigned* __restrict__ nu)
{
    int blk = blockIdx.x;
    int s = blk / HB, b = blk % HB;
    int t = threadIdx.x;
    __shared__ unsigned hp[HB];
    __shared__ unsigned pre[HB + 1];
    if (t < HB) hp[t] = hpart[s * HB + t];
    __syncthreads();
    if (t == 0) {
        unsigned run = 0;
        for (int i = 0; i < HB; ++i) { pre[i] = run; run += hp[i]; }
        pre[HB] = run;
    }
    __syncthreads();
    int i = b * 512 + t;
    size_t base = (size_t)s * Vv;
    unsigned k = skeys[base + i];
    bool head = (i == 0) || (skeys[base + i - 1] != k);
    unsigned long long bal = __ballot(head);
    int lane = t & 63, wid = t >> 6;
    __shared__ unsigned wsum[8];
    if (lane == 0) wsum[wid] = (unsigned)__popcll(bal);
    __syncthreads();
    unsigned wbase = 0;
    for (int w = 0; w < wid; ++w) wbase += wsum[w];
    unsigned lpre = (unsigned)__popcll(bal & ((1ull << lane) - 1ull));
    if (head)
        start[(size_t)s * (Vv + 1) + pre[b] + wbase + lpre] = (unsigned)i;
    if (b == 0 && t == 0) {
        nu[s] = pre[HB];
        start[(size_t)s * (Vv + 1) + pre[HB]] = (unsigned)Vv;
    }
}

// ---------------- output build: 1 wave per output row, float4 feat ----------------
__global__ __launch_bounds__(256) void outputk(
    const unsigned* __restrict__ sidx, const unsigned* __restrict__ start,
    const unsigned* __restrict__ nu, const int* __restrict__ indb,
    const float* __restrict__ coor, const float* __restrict__ featb,
    float* __restrict__ out)
{
    int wid = threadIdx.x >> 6, lane = threadIdx.x & 63;
    int g = blockIdx.x * 4 + wid;
    int s = g / Vv, u = g - s * Vv;
    size_t su = (size_t)s * Vv + u;
    bool valid = (unsigned)u < nu[s];
    float4* out4 = (float4*)out;
    int f = lane & 31, jlo = lane >> 5;
    if (valid) {
        const unsigned* st = start + (size_t)s * (Vv + 1);
        unsigned i0 = st[u], i1 = st[u + 1];
        unsigned c = i1 - i0;
        unsigned my = sidx[(size_t)s * Vv + i0 + ((unsigned)(lane & 3)) % c];
        unsigned sv[4];
        sv[0] = __shfl(my, 0); sv[1] = __shfl(my, 1);
        sv[2] = __shfl(my, 2); sv[3] = __shfl(my, 3);
        const float4* fb = (const float4*)(featb + (size_t)s * Nn * Cc);
        #pragma unroll
        for (int h = 0; h < 2; ++h) {
            int j = jlo + 2 * h;
            out4[(FEAT0 >> 2) + su * 128 + (size_t)j * 32 + f] =
                fb[(size_t)(sv[j] / 3) * 32 + f];
        }
        if (lane < 12)
            out[COOR0 + su * 12 + lane] =
                coor[((size_t)s * Vv + sv[lane / 3]) * 3 + lane % 3];
        else if (lane < 15)
            out[IND0 + su * 3 + (lane - 12)] =
                (float)indb[((size_t)s * Vv + sv[0]) * 3 + (lane - 12)];
        else if (lane == 15)
            out[MASK0 + su] = 1.f;
    } else {
        float4 z = make_float4(0.f, 0.f, 0.f, 0.f);
        #pragma unroll
        for (int h = 0; h < 2; ++h)
            out4[(FEAT0 >> 2) + su * 128 + (size_t)(jlo + 2 * h) * 32 + f] = z;
        if (lane < 12)       out[COOR0 + su * 12 + lane] = 0.f;
        else if (lane < 15)  out[IND0 + su * 3 + (lane - 12)] = 0.f;
        else if (lane == 15) out[MASK0 + su] = 0.f;
    }
}

// ---------------- host launch ----------------
extern "C" void kernel_launch(void* const* d_in, const int* in_sizes, int n_in,
                              void* d_out, int out_size, void* d_ws, size_t ws_size,
                              hipStream_t stream)
{
    const int*   ID  = (const int*)d_in[0];
    const float* CO  = (const float*)d_in[1];
    const float* FT  = (const float*)d_in[2];
    const float* W1  = (const float*)d_in[3];
    const float* b1  = (const float*)d_in[4];
    const float* g1  = (const float*)d_in[5];
    const float* be1 = (const float*)d_in[6];
    const float* W2  = (const float*)d_in[7];
    const float* b2  = (const float*)d_in[8];
    const float* g2  = (const float*)d_in[9];
    const float* be2 = (const float*)d_in[10];
    const float* W3  = (const float*)d_in[11];
    const float* b3  = (const float*)d_in[12];
    float* out = (float*)d_out;

    char* wsc = (char*)d_ws;
    size_t off = 0;
    auto alloc = [&](size_t elems) -> void* {
        void* p = wsc + off;
        off += ((elems * 4 + 255) & ~(size_t)255);
        return p;
    };
    float*    H1b   = (float*)alloc((size_t)Bn * Nn * Cc);
    float*    H2b   = (float*)alloc((size_t)Bn * Nn * Cc);
    float*    PART  = (float*)alloc((size_t)Bn * 64 * 2 * Cc);
    float*    SS    = (float*)alloc((size_t)Bn * 2 * Cc);
    float*    COORb = (float*)alloc((size_t)Bn * Vv * 3);
    int*      INDB  = (int*)alloc((size_t)Bn * Vv * 3);
    float*    FEATB = (float*)alloc((size_t)Bn * Nn * Cc);
    unsigned* KA    = (unsigned*)alloc((size_t)Bn * Vv);
    unsigned* IA    = (unsigned*)alloc((size_t)Bn * Vv);
    unsigned* KB    = (unsigned*)alloc((size_t)Bn * Vv);
    unsigned* IB    = (unsigned*)alloc((size_t)Bn * Vv);
    unsigned* H0h   = (unsigned*)alloc((size_t)Bn * SB * 1024);  // three hist buffers,
    unsigned* H1h   = (unsigned*)alloc((size_t)Bn * SB * 1024);  // contiguous (sizes are
    unsigned* H2h   = (unsigned*)alloc((size_t)Bn * SB * 1024);  // multiples of 256B)
    unsigned* HP    = (unsigned*)alloc((size_t)Bn * HB);
    unsigned* NUp   = (unsigned*)alloc((size_t)Bn);
    unsigned* STp   = (unsigned*)alloc((size_t)Bn * (Vv + 1));
    (void)in_sizes; (void)n_in; (void)out_size; (void)ws_size;

    // zero all 3 hist buffers: 3 * Bn*SB*1024 u32 = 294912 u32 = 73728 uint4
    zerok<<<288, 256, 0, stream>>>((uint4*)H0h);

    // MLP (BN fused into next layer's A-load; stats byte-identical)
    gemm_t<false><<<Bn * 256, 256, 0, stream>>>(FT, W1, b1, nullptr, H1b);
    colstats<<<Bn * 64, 128, 0, stream>>>(H1b, PART);
    bnfinalize<<<Bn, 128, 0, stream>>>(PART, g1, be1, SS);
    gemm_t<true><<<Bn * 256, 256, 0, stream>>>(H1b, W2, b2, SS, H2b);
    colstats<<<Bn * 64, 128, 0, stream>>>(H2b, PART);
    bnfinalize<<<Bn, 128, 0, stream>>>(PART, g2, be2, SS);

    // layer 3 + fused vote prep (writes featb/coor/ind/keys/hist0 directly)
    gemm3_fused<<<Bn * 256, 256, 0, stream>>>(H2b, W3, b3, SS, FT, CO, ID,
                                              FEATB, COORb, INDB, KA, IA, H0h);

    // radix sort: 3 x 10-bit, scan fused into scatter, hist fused into prev pass
    scat<0><<<Bn * SB, 512, 0, stream>>>(KA, IA, KB, IB, H0h, H1h);
    scat<1><<<Bn * SB, 512, 0, stream>>>(KB, IB, KA, IA, H1h, H2h);
    scat<2><<<Bn * SB, 512, 0, stream>>>(KA, IA, KB, IB, H2h, nullptr);

    // grouping
    headsct<<<Bn * HB, 512, 0, stream>>>(KB, HP);
    ranksk<<<Bn * HB, 512, 0, stream>>>(KB, HP, STp, NUp);

    // output
    outputk<<<Bn * Vv / 4, 256, 0, stream>>>(IB, STp, NUp, INDB, COORb, FEATB, out);
}